// Round 7
// baseline (982.450 us; speedup 1.0000x reference)
//
#include <hip/hip_runtime.h>
#include <math.h>

// Problem constants (B=2, H=16, L=2048, D=128, fp32 in/out, int32 mask)
constexpr int Bc_ = 2;
constexpr int Hc_ = 16;
constexpr int Lc_ = 2048;
constexpr int Dc_ = 128;
constexpr int BR  = 128;  // Q rows per block (4 waves x 32 rows, 32x32 MFMA)
constexpr int BC  = 32;   // K rows per tile
// 1/sqrt(128) * log2(e): exp(x) == exp2(x*log2e); fold log2e into Q pre-scale.
constexpr float SCALE_LOG2E = 0.08838834764831845f * 1.4426950408889634f;

typedef __attribute__((ext_vector_type(8)))  short        bf16x8;
typedef __attribute__((ext_vector_type(4)))  float        f32x4;
typedef __attribute__((ext_vector_type(16))) float        f32x16;
typedef __attribute__((ext_vector_type(4)))  int          i32x4;
typedef __attribute__((ext_vector_type(4)))  unsigned int u32x4;

// fp32 -> bf16 RNE (scalar; only for the one-time Q fragment build)
__device__ __forceinline__ unsigned short f2bf(float f) {
  unsigned u = __builtin_bit_cast(unsigned, f);
  return (unsigned short)((u + 0x7fffu + ((u >> 16) & 1u)) >> 16);
}

// packed fp32x2 -> bf16x2 in ONE VALU op
__device__ __forceinline__ unsigned cvt_pk_bf16(float lo, float hi) {
  unsigned r;
  asm("v_cvt_pk_bf16_f32 %0, %1, %2" : "=v"(r) : "v"(lo), "v"(hi));
  return r;
}

// Workgroup barrier that does NOT drain vmcnt (unlike __syncthreads).
// LDS visibility needs lgkmcnt(0) only; register-prefetch global loads
// stay in flight across the barrier.
__device__ __forceinline__ void barrier_lgkm() {
  asm volatile("s_waitcnt lgkmcnt(0)\n\ts_barrier" ::: "memory");
}

constexpr int KS_STRIDE = 136;  // K tile rows (shorts)
constexpr int VT_STRIDE = 40;   // V^T rows (shorts, 32 k-cols + 8 pad)
constexpr int PM_STRIDE = 65;   // packed-mask row stride in dwords (+1 pad
                                //  -> 32 q-rows at same word hit 32 banks)

// XOR swizzle (shorts): rows r, r+8, r+16, r+24 (same base bank-phase) get
// 4 distinct 16B slots. Applied identically on write and read.
__device__ __forceinline__ int swz(int row, int colShorts) {
  return colShorts ^ (((row >> 3) & 3) << 3);
}

// ===========================================================================
// Single-kernel design (round 7).
// Prologue: per-block mask pre-pass. The block's 128 mask rows are read
//   FULLY CONTIGUOUSLY (consecutive lanes -> consecutive 16B chunks of one
//   row; a wave streams whole 8KB rows) and bit-packed into LDS (32 KB).
//   This converts the main loop's DRAM-hostile 128B-per-8KB-stride mask
//   pattern (measured ~1.45 TB/s effective in R0) into one clean ~537 MB
//   stream chip-wide (~85 us) + one ds_read_b32 per lane per tile.
//   No workspace needed -> no silent-fallback ambiguity (R5/R6 lesson).
// Main loop: double-buffered K/V LDS, ONE barrier per tile:
//   phase t: {read PM word | QK from buf[t&1] | stage regs(tile t+1) ->
//   buf[(t+1)&1] | issue loads tile t+3 | softmax | PV from buf[t&1] |
//   lgkmcnt(0); s_barrier}.  LDS write->read separation = a full phase;
//   global-load issue->use = 2 phases.
// ===========================================================================

// one phase. T = tile index (0..63), BUFR/BUFW = LDS buffer indices,
// KRS/VRS = register set holding tile T+1 (staged here, then refilled with
// tile T+3).
#define PHASE(T, BUFR, BUFW, KRS, VRS)                                      \
  {                                                                         \
    /* 0. this lane's packed mask word for tile T (LDS, conflict-free) */   \
    const unsigned mcw = PMs[pm_row_off + (T)];                             \
    /* 1. S^T = K (Q*scale)^T : 8 chained MFMAs over d, K from buf[BUFR] */ \
    f32x16 s = (f32x16)0.0f;                                                \
    _Pragma("unroll")                                                       \
    for (int st = 0; st < 8; ++st) {                                        \
      const bf16x8 kf = *(const bf16x8*)&Ks[BUFR][l31 * KS_STRIDE + swz(l31, st * 16 + hi8)]; \
      s = __builtin_amdgcn_mfma_f32_32x32x16_bf16(kf, qf[st], s, 0, 0, 0);  \
    }                                                                       \
    /* 2. stage KRS/VRS (tile T+1, loaded 2 phases ago) -> buf[BUFW].       \
          BUFW was last READ at phase T-1 (pre-barrier) -> safe to write. */ \
    {                                                                       \
      u32x4 a, b;                                                           \
      a[0] = cvt_pk_bf16(KRS[0][0], KRS[0][1]);                             \
      a[1] = cvt_pk_bf16(KRS[0][2], KRS[0][3]);                             \
      a[2] = cvt_pk_bf16(KRS[1][0], KRS[1][1]);                             \
      a[3] = cvt_pk_bf16(KRS[1][2], KRS[1][3]);                             \
      b[0] = cvt_pk_bf16(KRS[2][0], KRS[2][1]);                             \
      b[1] = cvt_pk_bf16(KRS[2][2], KRS[2][3]);                             \
      b[2] = cvt_pk_bf16(KRS[3][0], KRS[3][1]);                             \
      b[3] = cvt_pk_bf16(KRS[3][2], KRS[3][3]);                             \
      *(u32x4*)&Ks[BUFW][krow * KS_STRIDE + swz(krow, kcg * 16)]     = a;   \
      *(u32x4*)&Ks[BUFW][krow * KS_STRIDE + swz(krow, kcg * 16 + 8)] = b;   \
    }                                                                       \
    _Pragma("unroll")                                                       \
    for (int c4 = 0; c4 < 4; ++c4) {                                        \
      const unsigned lov = cvt_pk_bf16(VRS[c4][0], VRS[c4][1]);             \
      const unsigned hiv = cvt_pk_bf16(VRS[c4][2], VRS[c4][3]);             \
      const int r0 = vcg * 16 + c4 * 4;                                     \
      Vt[BUFW][(r0 + 0) * VT_STRIDE + swz(r0 + 0, vrow)] = (unsigned short)lov; \
      Vt[BUFW][(r0 + 1) * VT_STRIDE + swz(r0 + 1, vrow)] = (unsigned short)(lov >> 16); \
      Vt[BUFW][(r0 + 2) * VT_STRIDE + swz(r0 + 2, vrow)] = (unsigned short)hiv; \
      Vt[BUFW][(r0 + 3) * VT_STRIDE + swz(r0 + 3, vrow)] = (unsigned short)(hiv >> 16); \
    }                                                                       \
    /* 3. refill the just-freed set with tile T+3 (2 phases of slack) */    \
    {                                                                       \
      const int kbn = (((T) + 3) & 63) * BC;                                \
      const float* kp = kbase_g + (size_t)kbn * Dc_;                        \
      const float* vp = vbase_g + (size_t)kbn * Dc_;                        \
      KRS[0] = *(const f32x4*)(kp + 0);  KRS[1] = *(const f32x4*)(kp + 4);  \
      KRS[2] = *(const f32x4*)(kp + 8);  KRS[3] = *(const f32x4*)(kp + 12); \
      VRS[0] = *(const f32x4*)(vp + 0);  VRS[1] = *(const f32x4*)(vp + 4);  \
      VRS[2] = *(const f32x4*)(vp + 8);  VRS[3] = *(const f32x4*)(vp + 12); \
    }                                                                       \
    /* 4. p = bit ? exp2(s) : 0 ; scalar row-sum; PV A-frags in register */ \
    bf16x8 pa0, pa1;                                                        \
    {                                                                       \
      const unsigned mw = mcw >> (hi * 4);                                  \
      const float p0  = (mw & 0x00000001u) ? exp2f(s[0])  : 0.0f;           \
      const float p1  = (mw & 0x00000002u) ? exp2f(s[1])  : 0.0f;           \
      const float p2  = (mw & 0x00000004u) ? exp2f(s[2])  : 0.0f;           \
      const float p3  = (mw & 0x00000008u) ? exp2f(s[3])  : 0.0f;           \
      const float p4  = (mw & 0x00000100u) ? exp2f(s[4])  : 0.0f;           \
      const float p5  = (mw & 0x00000200u) ? exp2f(s[5])  : 0.0f;           \
      const float p6  = (mw & 0x00000400u) ? exp2f(s[6])  : 0.0f;           \
      const float p7  = (mw & 0x00000800u) ? exp2f(s[7])  : 0.0f;           \
      const float p8  = (mw & 0x00010000u) ? exp2f(s[8])  : 0.0f;           \
      const float p9  = (mw & 0x00020000u) ? exp2f(s[9])  : 0.0f;           \
      const float p10 = (mw & 0x00040000u) ? exp2f(s[10]) : 0.0f;           \
      const float p11 = (mw & 0x00080000u) ? exp2f(s[11]) : 0.0f;           \
      const float p12 = (mw & 0x01000000u) ? exp2f(s[12]) : 0.0f;           \
      const float p13 = (mw & 0x02000000u) ? exp2f(s[13]) : 0.0f;           \
      const float p14 = (mw & 0x04000000u) ? exp2f(s[14]) : 0.0f;           \
      const float p15 = (mw & 0x08000000u) ? exp2f(s[15]) : 0.0f;           \
      lsum += (((p0 + p1) + (p2 + p3)) + ((p4 + p5) + (p6 + p7)))           \
            + (((p8 + p9) + (p10 + p11)) + ((p12 + p13) + (p14 + p15)));    \
      const unsigned c0 = cvt_pk_bf16(p0,  p1),  c1 = cvt_pk_bf16(p2,  p3); \
      const unsigned c2 = cvt_pk_bf16(p4,  p5),  c3 = cvt_pk_bf16(p6,  p7); \
      const unsigned c4 = cvt_pk_bf16(p8,  p9),  c5 = cvt_pk_bf16(p10, p11);\
      const unsigned c6 = cvt_pk_bf16(p12, p13), c7 = cvt_pk_bf16(p14, p15);\
      const unsigned x0 = (unsigned)__shfl_xor((int)c0, 32);                \
      const unsigned x1 = (unsigned)__shfl_xor((int)c1, 32);                \
      const unsigned x2 = (unsigned)__shfl_xor((int)c2, 32);                \
      const unsigned x3 = (unsigned)__shfl_xor((int)c3, 32);                \
      const unsigned x4 = (unsigned)__shfl_xor((int)c4, 32);                \
      const unsigned x5 = (unsigned)__shfl_xor((int)c5, 32);                \
      const unsigned x6 = (unsigned)__shfl_xor((int)c6, 32);                \
      const unsigned x7 = (unsigned)__shfl_xor((int)c7, 32);                \
      u32x4 a0, a1;                                                         \
      a0[0] = lo ? c0 : x2;  a0[1] = lo ? c1 : x3;                          \
      a0[2] = lo ? x0 : c2;  a0[3] = lo ? x1 : c3;                          \
      a1[0] = lo ? c4 : x6;  a1[1] = lo ? c5 : x7;                          \
      a1[2] = lo ? x4 : c6;  a1[3] = lo ? x5 : c7;                          \
      pa0 = __builtin_bit_cast(bf16x8, a0);                                 \
      pa1 = __builtin_bit_cast(bf16x8, a1);                                 \
    }                                                                       \
    /* 5. O += P V : B = V^T rows from buf[BUFR] */                         \
    _Pragma("unroll")                                                       \
    for (int nb = 0; nb < 4; ++nb) {                                        \
      const int vrw0 = nb * 32 + l31;                                       \
      const bf16x8 vf0 = *(const bf16x8*)&Vt[BUFR][vrw0 * VT_STRIDE + swz(vrw0, hi8)]; \
      acc[nb] = __builtin_amdgcn_mfma_f32_32x32x16_bf16(pa0, vf0, acc[nb], 0, 0, 0); \
      const bf16x8 vf1 = *(const bf16x8*)&Vt[BUFR][vrw0 * VT_STRIDE + swz(vrw0, 16 + hi8)]; \
      acc[nb] = __builtin_amdgcn_mfma_f32_32x32x16_bf16(pa1, vf1, acc[nb], 0, 0, 0); \
    }                                                                       \
    /* 6. ONE barrier per tile: publishes buf[BUFW] for phase T+1 */        \
    barrier_lgkm();                                                         \
  }

// launch_bounds(256, 2): ~200 est. live regs (qf 32 + acc 64 + 2x K/V 64 +
// temps). DO NOT raise waves/EU: (256,4) spilled 2.5 GB/dispatch (measured
// twice); (256,3) spilled with register prefetch (round 3).
// LDS: Ks 2x8704 + Vt 2x10240 + PMs 33280 = 71168 B -> 2 blocks/CU.
__global__ __launch_bounds__(256, 2) void attn_fwd(
    const float* __restrict__ Q, const float* __restrict__ K,
    const float* __restrict__ V, const int* __restrict__ Mask,
    float* __restrict__ Out) {
  const int qblk = blockIdx.x;
  const int bh   = blockIdx.y;
  const int tid  = threadIdx.x;
  const int w    = tid >> 6;
  const int lane = tid & 63;
  const int l31  = lane & 31;
  const int hi   = lane >> 5;
  const int hi8  = hi * 8;
  const bool lo  = (hi == 0);

  const float* Qg = Q + (size_t)bh * Lc_ * Dc_;
  const float* Kg = K + (size_t)bh * Lc_ * Dc_;
  const float* Vg = V + (size_t)bh * Lc_ * Dc_;
  const int*   Mg = Mask + (size_t)bh * Lc_ * Lc_;
  float*       Og = Out + (size_t)bh * Lc_ * Dc_;

  const int qr0 = qblk * BR + w * 32;

  __shared__ alignas(16) unsigned short Ks[2][BC * KS_STRIDE];
  __shared__ alignas(16) unsigned short Vt[2][Dc_ * VT_STRIDE];
  __shared__ unsigned PMs[BR * PM_STRIDE];

  // Staging thread mappings
  const int krow = tid >> 3;   // 0..31, 8 threads/row
  const int kcg  = tid & 7;
  const int vrow = tid & 31;
  const int vcg  = tid >> 5;

  const float* kbase_g = Kg + (size_t)krow * Dc_ + kcg * 16;
  const float* vbase_g = Vg + (size_t)vrow * Dc_ + vcg * 16;

  // 2-deep K/V register sets: set[m&1] holds tile m.
  f32x4 kr0[4], vr0[4], kr1[4], vr1[4];

  // ---- issue tiles 0,1 immediately (land during the mask pre-pass) ----
  {
    const float* kp = kbase_g;               const float* vp = vbase_g;
    kr0[0] = *(const f32x4*)(kp + 0);  kr0[1] = *(const f32x4*)(kp + 4);
    kr0[2] = *(const f32x4*)(kp + 8);  kr0[3] = *(const f32x4*)(kp + 12);
    vr0[0] = *(const f32x4*)(vp + 0);  vr0[1] = *(const f32x4*)(vp + 4);
    vr0[2] = *(const f32x4*)(vp + 8);  vr0[3] = *(const f32x4*)(vp + 12);
  }
  {
    const float* kp = kbase_g + (size_t)BC * Dc_;
    const float* vp = vbase_g + (size_t)BC * Dc_;
    kr1[0] = *(const f32x4*)(kp + 0);  kr1[1] = *(const f32x4*)(kp + 4);
    kr1[2] = *(const f32x4*)(kp + 8);  kr1[3] = *(const f32x4*)(kp + 12);
    vr1[0] = *(const f32x4*)(vp + 0);  vr1[1] = *(const f32x4*)(vp + 4);
    vr1[2] = *(const f32x4*)(vp + 8);  vr1[3] = *(const f32x4*)(vp + 12);
  }

  // ---- Q fragments (B-operand of 32x32x16), loaded once, pre-scaled ----
  bf16x8 qf[8];
  {
    const float* qrow = Qg + (size_t)(qr0 + l31) * Dc_ + hi8;
#pragma unroll
    for (int st = 0; st < 8; ++st) {
      const f32x4 a = *(const f32x4*)(qrow + st * 16);
      const f32x4 b = *(const f32x4*)(qrow + st * 16 + 4);
      bf16x8 f;
      f[0] = (short)f2bf(a[0] * SCALE_LOG2E); f[1] = (short)f2bf(a[1] * SCALE_LOG2E);
      f[2] = (short)f2bf(a[2] * SCALE_LOG2E); f[3] = (short)f2bf(a[3] * SCALE_LOG2E);
      f[4] = (short)f2bf(b[0] * SCALE_LOG2E); f[5] = (short)f2bf(b[1] * SCALE_LOG2E);
      f[6] = (short)f2bf(b[2] * SCALE_LOG2E); f[7] = (short)f2bf(b[3] * SCALE_LOG2E);
      qf[st] = f;
    }
  }

  // ---- mask pre-pass: 128 rows x 2048 cols -> 1 bit/elem in LDS.
  // idx = tid + 256*i: row = idx>>6, word = idx&63. Consecutive lanes read
  // consecutive 128B chunks of the SAME row -> perfectly coalesced stream.
#pragma unroll 2
  for (int i = 0; i < 32; ++i) {
    const int idx  = tid + 256 * i;
    const int row  = idx >> 6;
    const int word = idx & 63;
    const int* mp = Mg + (size_t)(qblk * BR + row) * Lc_ + word * 32;
    unsigned wb = 0;
#pragma unroll
    for (int c4 = 0; c4 < 8; ++c4) {
      const i32x4 m = __builtin_nontemporal_load((const i32x4*)(mp + c4 * 4));
      wb |= (m[0] != 0 ? 1u : 0u) << (c4 * 4 + 0);
      wb |= (m[1] != 0 ? 1u : 0u) << (c4 * 4 + 1);
      wb |= (m[2] != 0 ? 1u : 0u) << (c4 * 4 + 2);
      wb |= (m[3] != 0 ? 1u : 0u) << (c4 * 4 + 3);
    }
    PMs[row * PM_STRIDE + word] = wb;
  }

  f32x16 acc[4];
#pragma unroll
  for (int i = 0; i < 4; ++i) acc[i] = (f32x16)0.0f;
  float lsum = 0.0f;

  const int pm_row_off = (w * 32 + l31) * PM_STRIDE;

  // ---- stage tile 0 -> buf0 (vmcnt auto-wait), refill set0 with tile 2 ----
  {
    u32x4 a, b;
    a[0] = cvt_pk_bf16(kr0[0][0], kr0[0][1]);
    a[1] = cvt_pk_bf16(kr0[0][2], kr0[0][3]);
    a[2] = cvt_pk_bf16(kr0[1][0], kr0[1][1]);
    a[3] = cvt_pk_bf16(kr0[1][2], kr0[1][3]);
    b[0] = cvt_pk_bf16(kr0[2][0], kr0[2][1]);
    b[1] = cvt_pk_bf16(kr0[2][2], kr0[2][3]);
    b[2] = cvt_pk_bf16(kr0[3][0], kr0[3][1]);
    b[3] = cvt_pk_bf16(kr0[3][2], kr0[3][3]);
    *(u32x4*)&Ks[0][krow * KS_STRIDE + swz(krow, kcg * 16)]     = a;
    *(u32x4*)&Ks[0][krow * KS_STRIDE + swz(krow, kcg * 16 + 8)] = b;
#pragma unroll
    for (int c4 = 0; c4 < 4; ++c4) {
      const unsigned lov = cvt_pk_bf16(vr0[c4][0], vr0[c4][1]);
      const unsigned hiv = cvt_pk_bf16(vr0[c4][2], vr0[c4][3]);
      const int r0 = vcg * 16 + c4 * 4;
      Vt[0][(r0 + 0) * VT_STRIDE + swz(r0 + 0, vrow)] = (unsigned short)lov;
      Vt[0][(r0 + 1) * VT_STRIDE + swz(r0 + 1, vrow)] = (unsigned short)(lov >> 16);
      Vt[0][(r0 + 2) * VT_STRIDE + swz(r0 + 2, vrow)] = (unsigned short)hiv;
      Vt[0][(r0 + 3) * VT_STRIDE + swz(r0 + 3, vrow)] = (unsigned short)(hiv >> 16);
    }
    const float* kp = kbase_g + (size_t)(2 * BC) * Dc_;
    const float* vp = vbase_g + (size_t)(2 * BC) * Dc_;
    kr0[0] = *(const f32x4*)(kp + 0);  kr0[1] = *(const f32x4*)(kp + 4);
    kr0[2] = *(const f32x4*)(kp + 8);  kr0[3] = *(const f32x4*)(kp + 12);
    vr0[0] = *(const f32x4*)(vp + 0);  vr0[1] = *(const f32x4*)(vp + 4);
    vr0[2] = *(const f32x4*)(vp + 8);  vr0[3] = *(const f32x4*)(vp + 12);
  }
  barrier_lgkm();  // publishes buf0 + PMs

  // ---- main loop: 64 phases, one barrier each.
  // Phase t: compute buf[t&1]; stage set[(t+1)&1] -> buf[(t+1)&1];
  // refill that set with tile t+3.
#pragma unroll 1
  for (int t = 0; t < 64; t += 2) {
    PHASE(t,     (t)&1,     (t+1)&1, kr1, vr1)
    PHASE(t + 1, (t+1)&1,   (t)&1,   kr0, vr0)
  }

  // ---- epilogue: combine k-halves' sums, normalize, store ----
  lsum += __shfl_xor(lsum, 32);
  const float inv = 1.0f / lsum;
#pragma unroll
  for (int r = 0; r < 16; ++r) {
    const int qrow_r = (r & 3) + 8 * (r >> 2) + 4 * hi;
    const float rinv = __shfl(inv, qrow_r);
    float* orow = Og + (size_t)(qr0 + qrow_r) * Dc_ + l31;
#pragma unroll
    for (int nb = 0; nb < 4; ++nb)
      __builtin_nontemporal_store(acc[nb][r] * rinv, orow + nb * 32);
  }
}

extern "C" void kernel_launch(void* const* d_in, const int* in_sizes, int n_in,
                              void* d_out, int out_size, void* d_ws, size_t ws_size,
                              hipStream_t stream) {
  const float* Q    = (const float*)d_in[0];
  const float* K    = (const float*)d_in[1];
  const float* V    = (const float*)d_in[2];
  const int*   Mask = (const int*)d_in[3];
  float*       Out  = (float*)d_out;
  (void)d_ws; (void)ws_size;  // workspace-free (R5/R6 fallback ambiguity fix)
  dim3 grid(Lc_ / BR, Bc_ * Hc_);
  attn_fwd<<<grid, dim3(256), 0, stream>>>(Q, K, V, Mask, Out);
}

// Round 8
// 855.124 us; speedup vs baseline: 1.1489x; 1.1489x over previous
//
#include <hip/hip_runtime.h>
#include <math.h>

// Problem constants (B=2, H=16, L=2048, D=128, fp32 in/out, int32 mask)
constexpr int Bc_ = 2;
constexpr int Hc_ = 16;
constexpr int Lc_ = 2048;
constexpr int Dc_ = 128;
constexpr int BR  = 128;  // Q rows per block (4 waves x 32 rows, 32x32 MFMA)
constexpr int BC  = 32;   // K rows per tile
// 1/sqrt(128) * log2(e): exp(x) == exp2(x*log2e); fold log2e into Q pre-scale.
constexpr float SCALE_LOG2E = 0.08838834764831845f * 1.4426950408889634f;

typedef __attribute__((ext_vector_type(8)))  short        bf16x8;
typedef __attribute__((ext_vector_type(4)))  float        f32x4;
typedef __attribute__((ext_vector_type(16))) float        f32x16;
typedef __attribute__((ext_vector_type(4)))  int          i32x4;
typedef __attribute__((ext_vector_type(4)))  unsigned int u32x4;

// fp32 -> bf16 RNE (scalar; only for the one-time Q fragment build)
__device__ __forceinline__ unsigned short f2bf(float f) {
  unsigned u = __builtin_bit_cast(unsigned, f);
  return (unsigned short)((u + 0x7fffu + ((u >> 16) & 1u)) >> 16);
}

// packed fp32x2 -> bf16x2 in ONE VALU op
__device__ __forceinline__ unsigned cvt_pk_bf16(float lo, float hi) {
  unsigned r;
  asm("v_cvt_pk_bf16_f32 %0, %1, %2" : "=v"(r) : "v"(lo), "v"(hi));
  return r;
}

// Workgroup barrier that does NOT drain vmcnt (unlike __syncthreads).
// LDS visibility needs lgkmcnt(0) only; register-prefetch global loads
// stay in flight across the barrier.
__device__ __forceinline__ void barrier_lgkm() {
  asm volatile("s_waitcnt lgkmcnt(0)\n\ts_barrier" ::: "memory");
}

constexpr int KS_STRIDE = 136;  // K tile rows (shorts)
constexpr int VT_STRIDE = 40;   // V^T rows (shorts, 32 k-cols + 8 pad)

// XOR swizzle (shorts): rows r, r+8, r+16, r+24 (same base bank-phase) get
// 4 distinct 16B slots. Applied identically on write and read (bijective,
// preserves 16B alignment of 8-short-aligned columns). R7-verified correct;
// measured SQ_LDS_BANK_CONFLICT 2.4e7 -> 1.47e7.
__device__ __forceinline__ int swz(int row, int colShorts) {
  return colShorts ^ (((row >> 3) & 3) << 3);
}

// ===========================================================================
// R8 = R4 (best-measured: attn ~295us) + s_setprio around MFMA clusters (T5,
// +4-7% attn per guide m191) + LDS XOR-swizzle (R7-verified). Nothing else
// changed: 1-deep K/V+mask register prefetch, 2 lgkm-barriers/tile, raw
// int32 mask loads (nontemporal), single kernel, no workspace.
// R7 lesson: mask pre-pass is net-negative (serializes what R4 overlapped,
// thrashes L3 -> FETCH 651->877 MB); dbuf/1-barrier/2-deep: no effect.
// ===========================================================================
#define TILE_BODY(KB, MC, MN)                                               \
  {                                                                         \
    /* 1. stage current K regs -> LDS (bf16, swizzled row-major) */         \
    {                                                                       \
      u32x4 a, b;                                                           \
      a[0] = cvt_pk_bf16(kr[0][0], kr[0][1]);                               \
      a[1] = cvt_pk_bf16(kr[0][2], kr[0][3]);                               \
      a[2] = cvt_pk_bf16(kr[1][0], kr[1][1]);                               \
      a[3] = cvt_pk_bf16(kr[1][2], kr[1][3]);                               \
      b[0] = cvt_pk_bf16(kr[2][0], kr[2][1]);                               \
      b[1] = cvt_pk_bf16(kr[2][2], kr[2][3]);                               \
      b[2] = cvt_pk_bf16(kr[3][0], kr[3][1]);                               \
      b[3] = cvt_pk_bf16(kr[3][2], kr[3][3]);                               \
      *(u32x4*)&Ks[krow * KS_STRIDE + swz(krow, kcg * 16)]     = a;         \
      *(u32x4*)&Ks[krow * KS_STRIDE + swz(krow, kcg * 16 + 8)] = b;         \
    }                                                                       \
    /* stage current V regs -> LDS transposed (scatter, swizzled) */        \
    _Pragma("unroll")                                                       \
    for (int c4 = 0; c4 < 4; ++c4) {                                        \
      const unsigned lov = cvt_pk_bf16(vr[c4][0], vr[c4][1]);               \
      const unsigned hiv = cvt_pk_bf16(vr[c4][2], vr[c4][3]);               \
      const int r0 = vcg * 16 + c4 * 4;                                     \
      Vt[(r0 + 0) * VT_STRIDE + swz(r0 + 0, vrow)] = (unsigned short)lov;   \
      Vt[(r0 + 1) * VT_STRIDE + swz(r0 + 1, vrow)] = (unsigned short)(lov >> 16); \
      Vt[(r0 + 2) * VT_STRIDE + swz(r0 + 2, vrow)] = (unsigned short)hiv;   \
      Vt[(r0 + 3) * VT_STRIDE + swz(r0 + 3, vrow)] = (unsigned short)(hiv >> 16); \
    }                                                                       \
    /* 2. issue next-tile K/V + mask loads (1-deep). All stay in flight     \
          across the lgkm-only barrier; tile body (~5k cyc) covers latency. */ \
    {                                                                       \
      const int kbn = ((KB) + BC) & (Lc_ - 1);                              \
      const float* kp = kbase_g + (size_t)kbn * Dc_;                        \
      const float* vp = vbase_g + (size_t)kbn * Dc_;                        \
      kr[0] = *(const f32x4*)(kp + 0);  kr[1] = *(const f32x4*)(kp + 4);    \
      kr[2] = *(const f32x4*)(kp + 8);  kr[3] = *(const f32x4*)(kp + 12);   \
      vr[0] = *(const f32x4*)(vp + 0);  vr[1] = *(const f32x4*)(vp + 4);    \
      vr[2] = *(const f32x4*)(vp + 8);  vr[3] = *(const f32x4*)(vp + 12);   \
      MN##0 = __builtin_nontemporal_load((const i32x4*)(mbase_g + kbn));      \
      MN##1 = __builtin_nontemporal_load((const i32x4*)(mbase_g + kbn + 8));  \
      MN##2 = __builtin_nontemporal_load((const i32x4*)(mbase_g + kbn + 16)); \
      MN##3 = __builtin_nontemporal_load((const i32x4*)(mbase_g + kbn + 24)); \
    }                                                                       \
    /* 3. barrier (lgkm only) — publishes Ks/Vt */                          \
    barrier_lgkm();                                                         \
    /* 4. S^T = K (Q*scale)^T : one 32x32 tile, 8 chained MFMAs over d */   \
    f32x16 s = (f32x16)0.0f;                                                \
    __builtin_amdgcn_s_setprio(1);                                          \
    _Pragma("unroll")                                                       \
    for (int st = 0; st < 8; ++st) {                                        \
      const bf16x8 kf = *(const bf16x8*)&Ks[l31 * KS_STRIDE + swz(l31, st * 16 + hi8)]; \
      s = __builtin_amdgcn_mfma_f32_32x32x16_bf16(kf, qf[st], s, 0, 0, 0);  \
    }                                                                       \
    __builtin_amdgcn_s_setprio(0);                                          \
    /* 5. p = mask ? exp2(s) : 0 ; per-lane scalar row-sum; PV A-frags in   \
          register via cvt_pk + cross-half exchange (no LDS). */            \
    bf16x8 pa0, pa1;                                                        \
    {                                                                       \
      const float p0  = ((MC##0)[0] != 0) ? exp2f(s[0])  : 0.0f;            \
      const float p1  = ((MC##0)[1] != 0) ? exp2f(s[1])  : 0.0f;            \
      const float p2  = ((MC##0)[2] != 0) ? exp2f(s[2])  : 0.0f;            \
      const float p3  = ((MC##0)[3] != 0) ? exp2f(s[3])  : 0.0f;            \
      const float p4  = ((MC##1)[0] != 0) ? exp2f(s[4])  : 0.0f;            \
      const float p5  = ((MC##1)[1] != 0) ? exp2f(s[5])  : 0.0f;            \
      const float p6  = ((MC##1)[2] != 0) ? exp2f(s[6])  : 0.0f;            \
      const float p7  = ((MC##1)[3] != 0) ? exp2f(s[7])  : 0.0f;            \
      const float p8  = ((MC##2)[0] != 0) ? exp2f(s[8])  : 0.0f;            \
      const float p9  = ((MC##2)[1] != 0) ? exp2f(s[9])  : 0.0f;            \
      const float p10 = ((MC##2)[2] != 0) ? exp2f(s[10]) : 0.0f;            \
      const float p11 = ((MC##2)[3] != 0) ? exp2f(s[11]) : 0.0f;            \
      const float p12 = ((MC##3)[0] != 0) ? exp2f(s[12]) : 0.0f;            \
      const float p13 = ((MC##3)[1] != 0) ? exp2f(s[13]) : 0.0f;            \
      const float p14 = ((MC##3)[2] != 0) ? exp2f(s[14]) : 0.0f;            \
      const float p15 = ((MC##3)[3] != 0) ? exp2f(s[15]) : 0.0f;            \
      lsum += (((p0 + p1) + (p2 + p3)) + ((p4 + p5) + (p6 + p7)))           \
            + (((p8 + p9) + (p10 + p11)) + ((p12 + p13) + (p14 + p15)));    \
      const unsigned c0 = cvt_pk_bf16(p0,  p1),  c1 = cvt_pk_bf16(p2,  p3); \
      const unsigned c2 = cvt_pk_bf16(p4,  p5),  c3 = cvt_pk_bf16(p6,  p7); \
      const unsigned c4 = cvt_pk_bf16(p8,  p9),  c5 = cvt_pk_bf16(p10, p11);\
      const unsigned c6 = cvt_pk_bf16(p12, p13), c7 = cvt_pk_bf16(p14, p15);\
      const unsigned x0 = (unsigned)__shfl_xor((int)c0, 32);                \
      const unsigned x1 = (unsigned)__shfl_xor((int)c1, 32);                \
      const unsigned x2 = (unsigned)__shfl_xor((int)c2, 32);                \
      const unsigned x3 = (unsigned)__shfl_xor((int)c3, 32);                \
      const unsigned x4 = (unsigned)__shfl_xor((int)c4, 32);                \
      const unsigned x5 = (unsigned)__shfl_xor((int)c5, 32);                \
      const unsigned x6 = (unsigned)__shfl_xor((int)c6, 32);                \
      const unsigned x7 = (unsigned)__shfl_xor((int)c7, 32);                \
      u32x4 a0, a1;                                                         \
      a0[0] = lo ? c0 : x2;  a0[1] = lo ? c1 : x3;                          \
      a0[2] = lo ? x0 : c2;  a0[3] = lo ? x1 : c3;                          \
      a1[0] = lo ? c4 : x6;  a1[1] = lo ? c5 : x7;                          \
      a1[2] = lo ? x4 : c6;  a1[3] = lo ? x5 : c7;                          \
      pa0 = __builtin_bit_cast(bf16x8, a0);                                 \
      pa1 = __builtin_bit_cast(bf16x8, a1);                                 \
    }                                                                       \
    /* 6. O += P V : 4 d-blocks x 2 k-halves, B = V^T rows from LDS */      \
    __builtin_amdgcn_s_setprio(1);                                          \
    _Pragma("unroll")                                                       \
    for (int nb = 0; nb < 4; ++nb) {                                        \
      const int vrw0 = nb * 32 + l31;                                       \
      const bf16x8 vf0 = *(const bf16x8*)&Vt[vrw0 * VT_STRIDE + swz(vrw0, hi8)]; \
      acc[nb] = __builtin_amdgcn_mfma_f32_32x32x16_bf16(pa0, vf0, acc[nb], 0, 0, 0); \
      const bf16x8 vf1 = *(const bf16x8*)&Vt[vrw0 * VT_STRIDE + swz(vrw0, 16 + hi8)]; \
      acc[nb] = __builtin_amdgcn_mfma_f32_32x32x16_bf16(pa1, vf1, acc[nb], 0, 0, 0); \
    }                                                                       \
    __builtin_amdgcn_s_setprio(0);                                          \
    /* 7. protect LDS before next overwrite */                              \
    barrier_lgkm();                                                         \
  }

// launch_bounds(256, 2): ~130 est. live regs. DO NOT raise waves/EU:
// (256,4) spilled 2.5 GB/dispatch (measured twice); (256,3) spilled with
// 3-deep register prefetch (round 3). Grid 512 = exactly 2 blocks/CU.
// LDS: Ks 8704 + Vt 10240 = 18944 B.
__global__ __launch_bounds__(256, 2) void attn_fwd(
    const float* __restrict__ Q, const float* __restrict__ K,
    const float* __restrict__ V, const int* __restrict__ Mask,
    float* __restrict__ Out) {
  const int qblk = blockIdx.x;
  const int bh   = blockIdx.y;
  const int tid  = threadIdx.x;
  const int w    = tid >> 6;
  const int lane = tid & 63;
  const int l31  = lane & 31;
  const int hi   = lane >> 5;
  const int hi8  = hi * 8;
  const bool lo  = (hi == 0);

  const float* Qg = Q + (size_t)bh * Lc_ * Dc_;
  const float* Kg = K + (size_t)bh * Lc_ * Dc_;
  const float* Vg = V + (size_t)bh * Lc_ * Dc_;
  const int*   Mg = Mask + (size_t)bh * Lc_ * Lc_;
  float*       Og = Out + (size_t)bh * Lc_ * Dc_;

  const int qr0 = qblk * BR + w * 32;

  __shared__ alignas(16) unsigned short Ks[BC * KS_STRIDE];
  __shared__ alignas(16) unsigned short Vt[Dc_ * VT_STRIDE];

  // ---- Q fragments (B-operand of 32x32x16), loaded once, pre-scaled ----
  bf16x8 qf[8];
  {
    const float* qrow = Qg + (size_t)(qr0 + l31) * Dc_ + hi8;
#pragma unroll
    for (int st = 0; st < 8; ++st) {
      const f32x4 a = *(const f32x4*)(qrow + st * 16);
      const f32x4 b = *(const f32x4*)(qrow + st * 16 + 4);
      bf16x8 f;
      f[0] = (short)f2bf(a[0] * SCALE_LOG2E); f[1] = (short)f2bf(a[1] * SCALE_LOG2E);
      f[2] = (short)f2bf(a[2] * SCALE_LOG2E); f[3] = (short)f2bf(a[3] * SCALE_LOG2E);
      f[4] = (short)f2bf(b[0] * SCALE_LOG2E); f[5] = (short)f2bf(b[1] * SCALE_LOG2E);
      f[6] = (short)f2bf(b[2] * SCALE_LOG2E); f[7] = (short)f2bf(b[3] * SCALE_LOG2E);
      qf[st] = f;
    }
  }

  f32x16 acc[4];
#pragma unroll
  for (int i = 0; i < 4; ++i) acc[i] = (f32x16)0.0f;
  float lsum = 0.0f;

  const int krow = tid >> 3;   // 0..31, 8 threads/row (coalesced 64B)
  const int kcg  = tid & 7;
  const int vrow = tid & 31;
  const int vcg  = tid >> 5;

  const float* kbase_g = Kg + (size_t)krow * Dc_ + kcg * 16;
  const float* vbase_g = Vg + (size_t)vrow * Dc_ + vcg * 16;
  const int*   mbase_g = Mg + (size_t)(qr0 + l31) * Lc_ + hi * 4;

  f32x4 kr[4], vr[4];
  i32x4 mA0, mA1, mA2, mA3, mB0, mB1, mB2, mB3;

  kr[0] = *(const f32x4*)(kbase_g + 0);  kr[1] = *(const f32x4*)(kbase_g + 4);
  kr[2] = *(const f32x4*)(kbase_g + 8);  kr[3] = *(const f32x4*)(kbase_g + 12);
  vr[0] = *(const f32x4*)(vbase_g + 0);  vr[1] = *(const f32x4*)(vbase_g + 4);
  vr[2] = *(const f32x4*)(vbase_g + 8);  vr[3] = *(const f32x4*)(vbase_g + 12);
  mA0 = __builtin_nontemporal_load((const i32x4*)(mbase_g));
  mA1 = __builtin_nontemporal_load((const i32x4*)(mbase_g + 8));
  mA2 = __builtin_nontemporal_load((const i32x4*)(mbase_g + 16));
  mA3 = __builtin_nontemporal_load((const i32x4*)(mbase_g + 24));

#pragma unroll 1
  for (int kb = 0; kb < Lc_; kb += 2 * BC) {
    TILE_BODY(kb,      mA, mB)
    TILE_BODY(kb + BC, mB, mA)
  }

  // ---- epilogue: combine k-halves' sums, normalize, store ----
  lsum += __shfl_xor(lsum, 32);
  const float inv = 1.0f / lsum;
#pragma unroll
  for (int r = 0; r < 16; ++r) {
    const int qrow_r = (r & 3) + 8 * (r >> 2) + 4 * hi;
    const float rinv = __shfl(inv, qrow_r);
    float* orow = Og + (size_t)(qr0 + qrow_r) * Dc_ + l31;
#pragma unroll
    for (int nb = 0; nb < 4; ++nb)
      __builtin_nontemporal_store(acc[nb][r] * rinv, orow + nb * 32);
  }
}

extern "C" void kernel_launch(void* const* d_in, const int* in_sizes, int n_in,
                              void* d_out, int out_size, void* d_ws, size_t ws_size,
                              hipStream_t stream) {
  const float* Q    = (const float*)d_in[0];
  const float* K    = (const float*)d_in[1];
  const float* V    = (const float*)d_in[2];
  const int*   Mask = (const int*)d_in[3];
  float*       Out  = (float*)d_out;
  (void)d_ws; (void)ws_size;
  dim3 grid(Lc_ / BR, Bc_ * Hc_);
  attn_fwd<<<grid, dim3(256), 0, stream>>>(Q, K, V, Mask, Out);
}